// Round 1
// baseline (907.895 us; speedup 1.0000x reference)
//
#include <hip/hip_runtime.h>

#define S    8192
#define Dm   4096
#define E    64
#define CAP  128
#define CCH  16          // split-K chunks
#define KC   (Dm/CCH)    // 256 k per chunk
#define TBv  256         // tokens per K1 block
#define KSUB 64          // k sub-tile staged in LDS
#define XS_STRIDE 68     // padded LDS row stride (16B-aligned, breaks worst conflicts)

#define CW_OFF 1
#define DM_OFF (1 + (size_t)S*E*CAP)
#define EC_OFF (1 + 2*(size_t)S*E*CAP)

// ---------------- K0: transpose wg[64][4096] -> wt[4096][64] ----------------
__global__ void k0_transpose(const float* __restrict__ wg, float* __restrict__ wt) {
    const int e  = blockIdx.x >> 2;
    const int kb = (blockIdx.x & 3) * 1024;
    const int t  = threadIdx.x;
    const float4 v = *(const float4*)(wg + (size_t)e * Dm + kb + t * 4);
    wt[(size_t)(kb + t*4 + 0) * E + e] = v.x;
    wt[(size_t)(kb + t*4 + 1) * E + e] = v.y;
    wt[(size_t)(kb + t*4 + 2) * E + e] = v.z;
    wt[(size_t)(kb + t*4 + 3) * E + e] = v.w;
}

// ---------------- K1: partial logits. token per lane, acc[64] experts, ------
// ---------------- W rows wave-uniform (scalar loads) ------------------------
__global__ __launch_bounds__(256, 2)
void k1_partial(const float* __restrict__ x, const float* __restrict__ wt,
                float* __restrict__ part) {
    __shared__ float xs[TBv * XS_STRIDE];
    const int tb  = blockIdx.x >> 4;   // 0..31 token block
    const int c   = blockIdx.x & 15;   // 0..15 k chunk
    const int tid = threadIdx.x;       // == token within tile
    const int token = tb * TBv + tid;
    const int k0 = c * KC;

    float acc[E];
    #pragma unroll
    for (int e = 0; e < E; e++) acc[e] = 0.f;

    for (int su = 0; su < KC / KSUB; su++) {
        const int ks0 = k0 + su * KSUB;
        // stage 256 tokens x 64 k, coalesced float4
        {
            const int r0 = tid >> 4;    // 0..15
            const int c4 = tid & 15;    // 0..15
            #pragma unroll
            for (int i = 0; i < 16; i++) {
                const int row = i * 16 + r0;
                const float4 v = *(const float4*)(x + (size_t)(tb*TBv + row) * Dm + ks0 + c4*4);
                *(float4*)(xs + row * XS_STRIDE + c4 * 4) = v;
            }
        }
        __syncthreads();
        const float* wrow = wt + (size_t)ks0 * E;
        #pragma unroll 1
        for (int kk = 0; kk < KSUB; kk++) {
            const float xv = xs[tid * XS_STRIDE + kk];
            const float* wr = wrow + kk * E;   // wave-uniform address -> scalar loads
            #pragma unroll
            for (int e = 0; e < E; e++) acc[e] = fmaf(xv, wr[e], acc[e]);
        }
        __syncthreads();
    }
    float* dst = part + ((size_t)c * S + token) * E;
    #pragma unroll
    for (int e = 0; e < E; e += 4) {
        *(float4*)(dst + e) = make_float4(acc[e], acc[e+1], acc[e+2], acc[e+3]);
    }
}

// ---------------- K1b: reduce partials, softmax, argmax ----------------------
__global__ __launch_bounds__(256, 1)
void k1b_softmax(const float* __restrict__ part, float* __restrict__ gate_val,
                 int* __restrict__ idx1, int* __restrict__ counts,
                 float* __restrict__ me_part) {
    const int tid = threadIdx.x, wv = tid >> 6, ln = tid & 63;
    const int token = blockIdx.x * 4 + wv;
    float p = 0.f;
    #pragma unroll
    for (int c = 0; c < CCH; c++) p += part[((size_t)c * S + token) * E + ln];
    // argmax (max value, lowest index on ties) — matches jnp.argmax
    float v = p; int i = ln;
    #pragma unroll
    for (int off = 1; off < 64; off <<= 1) {
        float ov = __shfl_xor(v, off, 64);
        int   oi = __shfl_xor(i, off, 64);
        if (ov > v || (ov == v && oi < i)) { v = ov; i = oi; }
    }
    float g = __expf(p - v);
    float ssum = g;
    #pragma unroll
    for (int off = 1; off < 64; off <<= 1) ssum += __shfl_xor(ssum, off, 64);
    const float gate = g / ssum;
    __shared__ float gs[4][64];
    gs[wv][ln] = gate;
    __syncthreads();
    if (tid < 64)
        me_part[(size_t)blockIdx.x * E + tid] = gs[0][tid] + gs[1][tid] + gs[2][tid] + gs[3][tid];
    if (ln == 0) {
        gate_val[token] = 1.0f / ssum;   // exp(max-max)/ssum
        idx1[token] = i;
        atomicAdd(&counts[i], 1);
    }
}

// ---------------- K1c: me_part[2048][64] -> me_sum[64] -----------------------
__global__ void k1c_mesum(const float* __restrict__ me_part, float* __restrict__ me_sum) {
    __shared__ float red[4][64];
    const int tid = threadIdx.x;
    const int e = tid & 63, pr = tid >> 6;
    float s = 0.f;
    for (int b = pr; b < S / 4; b += 4) s += me_part[(size_t)b * E + e];
    red[pr][e] = s;
    __syncthreads();
    if (tid < 64) me_sum[tid] = red[0][tid] + red[1][tid] + red[2][tid] + red[3][tid];
}

// ---------------- K2: per-expert capacity selection + scatter ----------------
__device__ __forceinline__ int block_reduce_sum(int v, int* tmp4, int tid) {
    #pragma unroll
    for (int off = 1; off < 64; off <<= 1) v += __shfl_xor(v, off, 64);
    __syncthreads();
    if ((tid & 63) == 0) tmp4[tid >> 6] = v;
    __syncthreads();
    return tmp4[0] + tmp4[1] + tmp4[2] + tmp4[3];
}

__device__ __forceinline__ int block_scan_incl(int val, int* a, int* b, int tid, int* total) {
    __syncthreads();
    a[tid] = val;
    __syncthreads();
    int* src = a; int* dst = b;
    #pragma unroll
    for (int off = 1; off < 256; off <<= 1) {
        int v = src[tid];
        if (tid >= off) v += src[tid - off];
        dst[tid] = v;
        __syncthreads();
        int* t = src; src = dst; dst = t;
    }
    *total = src[255];
    return src[tid];
}

__global__ __launch_bounds__(256, 1)
void k2_select(const int* __restrict__ idx1, const float* __restrict__ gate_val,
               const float* __restrict__ noise, const int* __restrict__ counts,
               const float* __restrict__ me_sum, float* __restrict__ out) {
    const int e = blockIdx.x;
    const int tid = threadIdx.x;
    __shared__ unsigned short l_tok[S];
    __shared__ float l_ns[S];
    __shared__ int sa[256], sb[256];
    __shared__ int tmp4[4];

    // pass 1: count matches in my ordered chunk of 32 tokens
    int cnt = 0;
    #pragma unroll 1
    for (int j = 0; j < 32; j++) cnt += (idx1[tid * 32 + j] == e);
    int total_n;
    int incl = block_scan_incl(cnt, sa, sb, tid, &total_n);
    int pos = incl - cnt;
    const int n = total_n;
    // pass 2: ordered compaction (list is token-index ordered)
    #pragma unroll 1
    for (int j = 0; j < 32; j++) {
        const int s = tid * 32 + j;
        if (idx1[s] == e) {
            l_tok[pos] = (unsigned short)s;
            l_ns[pos]  = noise[(size_t)s * E + e];
            pos++;
        }
    }
    __syncthreads();

    if (tid == 0) out[EC_OFF + e] = (float)n;   // exp_counts (pre-capacity)

    // find 128th-largest noise value via binary search on positive-float bits
    unsigned int V = 0u;
    if (n > CAP) {
        unsigned int lo = 0u, hi = 0x3F800000u;   // [0, 1.0)
        while (hi - lo > 1u) {
            const unsigned int mid = (lo + hi) >> 1;
            int c = 0;
            for (int i2 = tid; i2 < n; i2 += 256)
                c += (__float_as_uint(l_ns[i2]) >= mid);
            const int cge = block_reduce_sum(c, tmp4, tid);
            if (cge >= CAP) lo = mid; else hi = mid;
        }
        V = lo;
    }

    // per-thread ordered chunk of the list
    const int m = (n + 255) >> 8;
    const int i_begin = min(n, tid * m);
    const int i_end   = min(n, i_begin + m);
    int gt_l = 0, eq_l = 0;
    for (int i2 = i_begin; i2 < i_end; i2++) {
        const unsigned int b = __float_as_uint(l_ns[i2]);
        gt_l += (b > V); eq_l += (b == V);
    }
    int tot_gt, tot_eq;
    const int incl_gt = block_scan_incl(gt_l, sa, sb, tid, &tot_gt);
    (void)incl_gt;
    const int incl_eq = block_scan_incl(eq_l, sa, sb, tid, &tot_eq);
    const int eq_excl = incl_eq - eq_l;
    const int take_eq = CAP - tot_gt;   // >= 0; ties go to lowest token index (jax top_k stable)
    // selected in my chunk
    const int sel_l = gt_l + max(0, min(eq_l, take_eq - eq_excl));
    int tot_sel;
    const int incl_sel = block_scan_incl(sel_l, sa, sb, tid, &tot_sel);
    int slot = incl_sel - sel_l;
    int eq_seen = eq_excl;
    for (int i2 = i_begin; i2 < i_end; i2++) {
        const unsigned int b = __float_as_uint(l_ns[i2]);
        bool sel;
        if (b > V) sel = true;
        else if (b == V) { sel = (eq_seen < take_eq); eq_seen++; }
        else sel = false;
        if (sel) {
            const int tok = l_tok[i2];
            const float g = gate_val[tok];
            const size_t off = (size_t)tok * (E * CAP) + (size_t)e * CAP + slot;
            out[CW_OFF + off] = g;
            out[DM_OFF + off] = 1.0f;
            slot++;
        }
    }

    // l_aux by block 0, wave 0 (counts are exact ints; me deterministic)
    if (e == 0 && tid < 64) {
        float la = (me_sum[tid] / (float)S) * ((float)counts[tid] / (float)S);
        #pragma unroll
        for (int off = 1; off < 64; off <<= 1) la += __shfl_xor(la, off, 64);
        if (tid == 0) out[0] = la * (float)E;
    }
}

extern "C" void kernel_launch(void* const* d_in, const int* in_sizes, int n_in,
                              void* d_out, int out_size, void* d_ws, size_t ws_size,
                              hipStream_t stream) {
    const float* x     = (const float*)d_in[0];
    const float* wg    = (const float*)d_in[1];
    const float* noise = (const float*)d_in[2];
    float* out = (float*)d_out;
    float* ws  = (float*)d_ws;

    float* gate_val = ws;                   // 8192 f32
    int*   idx1     = (int*)(ws + 8192);    // 8192 i32
    int*   counts   = (int*)(ws + 16384);   // 64 i32
    float* me_sum   = ws + 16448;           // 64 f32

    // scratch inside d_out's dispatch_mask region (zero-filled later anyway)
    float* dm_base = out + DM_OFF;
    float* wt      = dm_base;                        // 4096*64 = 262144 f32
    float* part    = dm_base + (size_t)Dm * E;       // 16*8192*64 = 8388608 f32
    float* me_part = part + (size_t)CCH * S * E;     // 2048*64 = 131072 f32

    hipMemsetAsync(counts, 0, 64 * sizeof(int), stream);
    k0_transpose<<<dim3(256), dim3(256), 0, stream>>>(wg, wt);
    k1_partial  <<<dim3(512), dim3(256), 0, stream>>>(x, wt, part);
    k1b_softmax <<<dim3(S/4), dim3(256), 0, stream>>>(part, gate_val, idx1, counts, me_part);
    k1c_mesum   <<<dim3(1),   dim3(256), 0, stream>>>(me_part, me_sum);
    hipMemsetAsync(out, 0, (size_t)out_size * sizeof(float), stream);
    k2_select   <<<dim3(E),   dim3(256), 0, stream>>>(idx1, gate_val, noise, counts, me_sum, out);
}

// Round 2
// 790.820 us; speedup vs baseline: 1.1480x; 1.1480x over previous
//
#include <hip/hip_runtime.h>

#define S    8192
#define Dm   4096
#define E    64
#define CAP  128
#define CCH  16          // split-K chunks
#define KC   (Dm/CCH)    // 256 k per chunk
#define TBv  256         // tokens per K1 block
#define KSUB 64          // k sub-tile staged in LDS
#define XS_STRIDE 65     // odd stride: bank = (tid+kk)%32, conflict-free reads

#define CW_OFF 1
#define DM_OFF (1 + (size_t)S*E*CAP)
#define EC_OFF (1 + 2*(size_t)S*E*CAP)

// ---------------- K0: transpose wg[64][4096] -> wt[4096][64] ----------------
__global__ void k0_transpose(const float* __restrict__ wg, float* __restrict__ wt) {
    const int e  = blockIdx.x >> 2;
    const int kb = (blockIdx.x & 3) * 1024;
    const int t  = threadIdx.x;
    const float4 v = *(const float4*)(wg + (size_t)e * Dm + kb + t * 4);
    wt[(size_t)(kb + t*4 + 0) * E + e] = v.x;
    wt[(size_t)(kb + t*4 + 1) * E + e] = v.y;
    wt[(size_t)(kb + t*4 + 2) * E + e] = v.z;
    wt[(size_t)(kb + t*4 + 3) * E + e] = v.w;
}

// ---------------- K1: partial logits. token per lane, acc[64] experts, ------
// ---------------- W rows wave-uniform (scalar s_load broadcast) -------------
__global__ __launch_bounds__(256, 2)
void k1_partial(const float* __restrict__ x, const float* __restrict__ wt,
                float* __restrict__ part) {
    __shared__ float xs[TBv * XS_STRIDE];
    const int tb  = blockIdx.x >> 4;   // 0..31 token block
    const int c   = blockIdx.x & 15;   // 0..15 k chunk
    const int tid = threadIdx.x;       // == token within tile
    const int token = tb * TBv + tid;
    const int k0 = c * KC;

    float acc[E];
    #pragma unroll
    for (int e = 0; e < E; e++) acc[e] = 0.f;

    for (int su = 0; su < KC / KSUB; su++) {
        const int ks0 = k0 + su * KSUB;
        // stage 256 tokens x 64 k; global float4, LDS scalar stores (stride 65)
        {
            const int r0 = tid >> 4;    // 0..15
            const int c4 = tid & 15;    // 0..15
            #pragma unroll
            for (int i = 0; i < 16; i++) {
                const int row = i * 16 + r0;
                const float4 v = *(const float4*)(x + (size_t)(tb*TBv + row) * Dm + ks0 + c4*4);
                float* p = xs + row * XS_STRIDE + c4 * 4;
                p[0] = v.x; p[1] = v.y; p[2] = v.z; p[3] = v.w;
            }
        }
        __syncthreads();
        const float* wrow = wt + (size_t)ks0 * E;
        #pragma unroll 4
        for (int kk = 0; kk < KSUB; kk++) {
            const float xv = xs[tid * XS_STRIDE + kk];
            const float* wr = wrow + kk * E;   // wave-uniform address -> scalar loads
            #pragma unroll
            for (int e = 0; e < E; e++) acc[e] = fmaf(xv, wr[e], acc[e]);
        }
        __syncthreads();
    }
    float* dst = part + ((size_t)c * S + token) * E;
    #pragma unroll
    for (int e = 0; e < E; e += 4) {
        *(float4*)(dst + e) = make_float4(acc[e], acc[e+1], acc[e+2], acc[e+3]);
    }
}

// ---------------- K1b: reduce partials, softmax, argmax, me atomics ----------
__global__ __launch_bounds__(256, 1)
void k1b_softmax(const float* __restrict__ part, float* __restrict__ gate_val,
                 int* __restrict__ idx1, int* __restrict__ counts,
                 float* __restrict__ me_sum) {
    const int tid = threadIdx.x, wv = tid >> 6, ln = tid & 63;
    const int token = blockIdx.x * 4 + wv;
    float p = 0.f;
    #pragma unroll
    for (int c = 0; c < CCH; c++) p += part[((size_t)c * S + token) * E + ln];
    // argmax (max value, lowest index on ties) — matches jnp.argmax
    float v = p; int i = ln;
    #pragma unroll
    for (int off = 1; off < 64; off <<= 1) {
        float ov = __shfl_xor(v, off, 64);
        int   oi = __shfl_xor(i, off, 64);
        if (ov > v || (ov == v && oi < i)) { v = ov; i = oi; }
    }
    float g = __expf(p - v);
    float ssum = g;
    #pragma unroll
    for (int off = 1; off < 64; off <<= 1) ssum += __shfl_xor(ssum, off, 64);
    const float gate = g / ssum;
    __shared__ float gs[4][64];
    gs[wv][ln] = gate;
    __syncthreads();
    if (tid < 64)
        atomicAdd(&me_sum[tid], gs[0][tid] + gs[1][tid] + gs[2][tid] + gs[3][tid]);
    if (ln == 0) {
        gate_val[token] = 1.0f / ssum;   // exp(max-max)/ssum
        idx1[token] = i;
        atomicAdd(&counts[i], 1);
    }
}

// ---------------- K2: per-expert capacity selection + scatter ----------------
__device__ __forceinline__ int block_reduce_sum(int v, int* tmp4, int tid) {
    #pragma unroll
    for (int off = 1; off < 64; off <<= 1) v += __shfl_xor(v, off, 64);
    __syncthreads();
    if ((tid & 63) == 0) tmp4[tid >> 6] = v;
    __syncthreads();
    return tmp4[0] + tmp4[1] + tmp4[2] + tmp4[3];
}

__device__ __forceinline__ int block_scan_incl(int val, int* a, int* b, int tid, int* total) {
    __syncthreads();
    a[tid] = val;
    __syncthreads();
    int* src = a; int* dst = b;
    #pragma unroll
    for (int off = 1; off < 256; off <<= 1) {
        int v = src[tid];
        if (tid >= off) v += src[tid - off];
        dst[tid] = v;
        __syncthreads();
        int* t = src; src = dst; dst = t;
    }
    *total = src[255];
    return src[tid];
}

__global__ __launch_bounds__(256, 1)
void k2_select(const int* __restrict__ idx1, const float* __restrict__ gate_val,
               const float* __restrict__ noise, const int* __restrict__ counts,
               const float* __restrict__ me_sum, float* __restrict__ out) {
    const int e = blockIdx.x;
    const int tid = threadIdx.x;
    __shared__ int idx_s[S];            // 32 KB, coalesced-staged
    __shared__ unsigned short l_tok[S]; // 16 KB
    __shared__ float l_ns[S];           // 32 KB
    __shared__ int sa[256], sb[256];
    __shared__ int tmp4[4];

    for (int i = tid; i < S; i += 256) idx_s[i] = idx1[i];
    __syncthreads();

    // pass 1: count matches in my ordered chunk of 32 tokens (int4 LDS reads)
    int cnt = 0;
    #pragma unroll
    for (int j4 = 0; j4 < 8; j4++) {
        const int4 q = *(const int4*)&idx_s[tid * 32 + j4 * 4];
        cnt += (q.x == e) + (q.y == e) + (q.z == e) + (q.w == e);
    }
    int total_n;
    int incl = block_scan_incl(cnt, sa, sb, tid, &total_n);
    int pos = incl - cnt;
    const int n = total_n;
    // pass 2: ordered compaction (list is token-index ordered)
    #pragma unroll
    for (int j4 = 0; j4 < 8; j4++) {
        const int4 q = *(const int4*)&idx_s[tid * 32 + j4 * 4];
        const int qv[4] = {q.x, q.y, q.z, q.w};
        #pragma unroll
        for (int u = 0; u < 4; u++) {
            const int s = tid * 32 + j4 * 4 + u;
            if (qv[u] == e) {
                l_tok[pos] = (unsigned short)s;
                l_ns[pos]  = noise[(size_t)s * E + e];
                pos++;
            }
        }
    }
    __syncthreads();

    if (tid == 0) out[EC_OFF + e] = (float)n;   // exp_counts (pre-capacity)

    // find 128th-largest noise value via binary search on positive-float bits
    unsigned int V = 0u;
    if (n > CAP) {
        unsigned int lo = 0u, hi = 0x3F800000u;   // [0, 1.0)
        while (hi - lo > 1u) {
            const unsigned int mid = (lo + hi) >> 1;
            int c = 0;
            for (int i2 = tid; i2 < n; i2 += 256)
                c += (__float_as_uint(l_ns[i2]) >= mid);
            const int cge = block_reduce_sum(c, tmp4, tid);
            if (cge >= CAP) lo = mid; else hi = mid;
        }
        V = lo;
    }

    // per-thread ordered chunk of the list
    const int m = (n + 255) >> 8;
    const int i_begin = min(n, tid * m);
    const int i_end   = min(n, i_begin + m);
    int gt_l = 0, eq_l = 0;
    for (int i2 = i_begin; i2 < i_end; i2++) {
        const unsigned int b = __float_as_uint(l_ns[i2]);
        gt_l += (b > V); eq_l += (b == V);
    }
    int tot_gt, tot_eq;
    const int incl_gt = block_scan_incl(gt_l, sa, sb, tid, &tot_gt);
    (void)incl_gt;
    const int incl_eq = block_scan_incl(eq_l, sa, sb, tid, &tot_eq);
    const int eq_excl = incl_eq - eq_l;
    const int take_eq = CAP - tot_gt;   // >= 0; ties go to lowest token index (jax top_k stable)
    const int sel_l = gt_l + max(0, min(eq_l, take_eq - eq_excl));
    int tot_sel;
    const int incl_sel = block_scan_incl(sel_l, sa, sb, tid, &tot_sel);
    int slot = incl_sel - sel_l;
    int eq_seen = eq_excl;
    for (int i2 = i_begin; i2 < i_end; i2++) {
        const unsigned int b = __float_as_uint(l_ns[i2]);
        bool sel;
        if (b > V) sel = true;
        else if (b == V) { sel = (eq_seen < take_eq); eq_seen++; }
        else sel = false;
        if (sel) {
            const int tok = l_tok[i2];
            const float g = gate_val[tok];
            const size_t off = (size_t)tok * (E * CAP) + (size_t)e * CAP + slot;
            out[CW_OFF + off] = g;
            out[DM_OFF + off] = 1.0f;
            slot++;
        }
    }

    // l_aux by block 0 (counts exact ints; me atomic order error ~1e-7, scalar)
    if (e == 0 && tid < 64) {
        float la = (me_sum[tid] / (float)S) * ((float)counts[tid] / (float)S);
        #pragma unroll
        for (int off = 1; off < 64; off <<= 1) la += __shfl_xor(la, off, 64);
        if (tid == 0) out[0] = la * (float)E;
    }
}

extern "C" void kernel_launch(void* const* d_in, const int* in_sizes, int n_in,
                              void* d_out, int out_size, void* d_ws, size_t ws_size,
                              hipStream_t stream) {
    const float* x     = (const float*)d_in[0];
    const float* wg    = (const float*)d_in[1];
    const float* noise = (const float*)d_in[2];
    float* out = (float*)d_out;
    float* ws  = (float*)d_ws;

    float* gate_val = ws;                   // 8192 f32
    int*   idx1     = (int*)(ws + 8192);    // 8192 i32
    int*   counts   = (int*)(ws + 16384);   // 64 i32
    float* me_sum   = ws + 16448;           // 64 f32

    // scratch inside d_out's dispatch_mask region (zero-filled later anyway)
    float* dm_base = out + DM_OFF;
    float* wt      = dm_base;                        // 4096*64 = 262144 f32
    float* part    = dm_base + (size_t)Dm * E;       // 16*8192*64 = 8388608 f32

    hipMemsetAsync(counts, 0, 128 * sizeof(int), stream);   // counts + me_sum
    k0_transpose<<<dim3(256), dim3(256), 0, stream>>>(wg, wt);
    k1_partial  <<<dim3(512), dim3(256), 0, stream>>>(x, wt, part);
    k1b_softmax <<<dim3(S/4), dim3(256), 0, stream>>>(part, gate_val, idx1, counts, me_sum);
    hipMemsetAsync(out, 0, (size_t)out_size * sizeof(float), stream);
    k2_select   <<<dim3(E),   dim3(256), 0, stream>>>(idx1, gate_val, noise, counts, me_sum, out);
}